// Round 1
// baseline (412.103 us; speedup 1.0000x reference)
//
#include <hip/hip_runtime.h>
#include <math.h>

#define K_DIM 8192
#define M_DIM 8192
#define N_DIM 8
#define KC 1024            // K-chunk staged in LDS for the GEMM kernel
#define RED_BLOCKS 2048    // blocks in the |W| reduction

// ---------------------------------------------------------------------------
// Kernel 1: partial sums of |W|. Grid-stride float4, per-block double partial.
// ---------------------------------------------------------------------------
__global__ __launch_bounds__(256) void k_abssum(const float4* __restrict__ W4,
                                                double* __restrict__ partials,
                                                int n4) {
    int tid = blockIdx.x * blockDim.x + threadIdx.x;
    int stride = gridDim.x * blockDim.x;
    float s0 = 0.f, s1 = 0.f, s2 = 0.f, s3 = 0.f;
    for (int i = tid; i < n4; i += stride) {
        float4 v = W4[i];
        s0 += fabsf(v.x); s1 += fabsf(v.y);
        s2 += fabsf(v.z); s3 += fabsf(v.w);
    }
    float s = (s0 + s1) + (s2 + s3);
    #pragma unroll
    for (int off = 32; off > 0; off >>= 1) s += __shfl_xor(s, off, 64);
    __shared__ float sm[4];
    if ((threadIdx.x & 63) == 0) sm[threadIdx.x >> 6] = s;
    __syncthreads();
    if (threadIdx.x == 0) {
        double t = ((double)sm[0] + (double)sm[1]) +
                   ((double)sm[2] + (double)sm[3]);
        partials[blockIdx.x] = t;
    }
}

// ---------------------------------------------------------------------------
// Kernel 2: final reduce -> s_w, w_deq (replicating reference fp32 ops).
// ---------------------------------------------------------------------------
__global__ __launch_bounds__(256) void k_final(const double* __restrict__ partials,
                                               int nparts,
                                               float* __restrict__ scal) {
    double s = 0.0;
    for (int i = threadIdx.x; i < nparts; i += 256) s += partials[i];
    #pragma unroll
    for (int off = 32; off > 0; off >>= 1) s += __shfl_xor(s, off, 64);
    __shared__ double sm[4];
    if ((threadIdx.x & 63) == 0) sm[threadIdx.x >> 6] = s;
    __syncthreads();
    if (threadIdx.x == 0) {
        double tot = (sm[0] + sm[1]) + (sm[2] + sm[3]);
        float meanf = (float)(tot / (double)((long long)M_DIM * K_DIM));
        float clipped = fmaxf(meanf, 1e-5f);
        float s_w = 1.0f / clipped;    // reference: s_w = 1/clip(mean,1e-5)
        float w_deq = 1.0f / s_w;      // reference: w_deq = 1/s_w (fp32 chain)
        scal[0] = s_w;
        scal[1] = w_deq;
    }
}

// ---------------------------------------------------------------------------
// Kernel 3: activation per-group (64) quantization. One wave == one group.
// x_hat = rint(x / a_scale) * a_scale,  a_scale = max(fmax|xg|/127, 1e-8)
// rintf == round-half-even == np.round; '/' is IEEE fp32 (no fast-math).
// ---------------------------------------------------------------------------
__global__ __launch_bounds__(256) void k_actq(const float* __restrict__ x,
                                              float* __restrict__ xh) {
    int idx = blockIdx.x * blockDim.x + threadIdx.x;   // 0 .. N*K-1
    float v = x[idx];
    float a = fabsf(v);
    #pragma unroll
    for (int off = 32; off > 0; off >>= 1) a = fmaxf(a, __shfl_xor(a, off, 64));
    float scale = fmaxf(a / 127.0f, 1e-8f);
    float q = rintf(v / scale);
    xh[idx] = q * scale;
}

// ---------------------------------------------------------------------------
// Kernel 4: streaming ternary GEMM. Block = 4 waves; each wave streams 4 W
// rows; x_hat staged in LDS per K-chunk. Memory-bound on W (256 MiB).
// ---------------------------------------------------------------------------
__device__ __forceinline__ float quant1(float w, float s_w) {
    // reference: clip(round(w*s_w), -1, 1); rintf = half-even like np.round
    return fminf(1.0f, fmaxf(-1.0f, rintf(w * s_w)));
}

__global__ __launch_bounds__(256) void k_gemm(const float* __restrict__ W,
                                              const float* __restrict__ xh,
                                              const float* __restrict__ scal,
                                              float* __restrict__ out) {
    __shared__ float lds[N_DIM * KC];   // 32 KiB
    const float s_w  = scal[0];
    const float w_deq = scal[1];
    const int wave = threadIdx.x >> 6;
    const int lane = threadIdx.x & 63;
    const int m0 = blockIdx.x * 16 + wave * 4;   // 4 rows per wave

    const float* Wr0 = W + (size_t)(m0 + 0) * K_DIM;
    const float* Wr1 = W + (size_t)(m0 + 1) * K_DIM;
    const float* Wr2 = W + (size_t)(m0 + 2) * K_DIM;
    const float* Wr3 = W + (size_t)(m0 + 3) * K_DIM;

    float acc[4][8];
    #pragma unroll
    for (int r = 0; r < 4; ++r)
        #pragma unroll
        for (int n = 0; n < 8; ++n) acc[r][n] = 0.0f;

    for (int c0 = 0; c0 < K_DIM; c0 += KC) {
        // stage x_hat[0:8, c0:c0+KC] into LDS (2048 float4, 8 per thread)
        #pragma unroll
        for (int i = 0; i < 8; ++i) {
            int idx = threadIdx.x + i * 256;      // float4 index 0..2047
            int n = idx >> 8;                     // / (KC/4)
            int kk4 = idx & 255;
            float4 v = *(const float4*)(xh + n * K_DIM + c0 + kk4 * 4);
            *(float4*)(lds + n * KC + kk4 * 4) = v;
        }
        __syncthreads();

        #pragma unroll
        for (int it = 0; it < KC / 256; ++it) {
            const int kk = it * 256 + lane * 4;
            const int k = c0 + kk;
            float4 w0 = *(const float4*)(Wr0 + k);
            float4 w1 = *(const float4*)(Wr1 + k);
            float4 w2 = *(const float4*)(Wr2 + k);
            float4 w3 = *(const float4*)(Wr3 + k);
            float4 xv[8];
            #pragma unroll
            for (int n = 0; n < 8; ++n)
                xv[n] = *(const float4*)(lds + n * KC + kk);

            float4 q0, q1, q2, q3;
            q0.x = quant1(w0.x, s_w); q0.y = quant1(w0.y, s_w);
            q0.z = quant1(w0.z, s_w); q0.w = quant1(w0.w, s_w);
            q1.x = quant1(w1.x, s_w); q1.y = quant1(w1.y, s_w);
            q1.z = quant1(w1.z, s_w); q1.w = quant1(w1.w, s_w);
            q2.x = quant1(w2.x, s_w); q2.y = quant1(w2.y, s_w);
            q2.z = quant1(w2.z, s_w); q2.w = quant1(w2.w, s_w);
            q3.x = quant1(w3.x, s_w); q3.y = quant1(w3.y, s_w);
            q3.z = quant1(w3.z, s_w); q3.w = quant1(w3.w, s_w);

            #pragma unroll
            for (int n = 0; n < 8; ++n) {
                acc[0][n] = fmaf(q0.x, xv[n].x, acc[0][n]);
                acc[0][n] = fmaf(q0.y, xv[n].y, acc[0][n]);
                acc[0][n] = fmaf(q0.z, xv[n].z, acc[0][n]);
                acc[0][n] = fmaf(q0.w, xv[n].w, acc[0][n]);
                acc[1][n] = fmaf(q1.x, xv[n].x, acc[1][n]);
                acc[1][n] = fmaf(q1.y, xv[n].y, acc[1][n]);
                acc[1][n] = fmaf(q1.z, xv[n].z, acc[1][n]);
                acc[1][n] = fmaf(q1.w, xv[n].w, acc[1][n]);
                acc[2][n] = fmaf(q2.x, xv[n].x, acc[2][n]);
                acc[2][n] = fmaf(q2.y, xv[n].y, acc[2][n]);
                acc[2][n] = fmaf(q2.z, xv[n].z, acc[2][n]);
                acc[2][n] = fmaf(q2.w, xv[n].w, acc[2][n]);
                acc[3][n] = fmaf(q3.x, xv[n].x, acc[3][n]);
                acc[3][n] = fmaf(q3.y, xv[n].y, acc[3][n]);
                acc[3][n] = fmaf(q3.z, xv[n].z, acc[3][n]);
                acc[3][n] = fmaf(q3.w, xv[n].w, acc[3][n]);
            }
        }
        __syncthreads();
    }

    // cross-lane reduction + store
    #pragma unroll
    for (int r = 0; r < 4; ++r) {
        #pragma unroll
        for (int n = 0; n < 8; ++n) {
            float v = acc[r][n];
            #pragma unroll
            for (int off = 32; off > 0; off >>= 1) v += __shfl_xor(v, off, 64);
            acc[r][n] = v;
        }
    }
    if (lane == 0) {
        #pragma unroll
        for (int r = 0; r < 4; ++r)
            #pragma unroll
            for (int n = 0; n < 8; ++n)
                out[n * M_DIM + (m0 + r)] = w_deq * acc[r][n];
    }
}

// ---------------------------------------------------------------------------
extern "C" void kernel_launch(void* const* d_in, const int* in_sizes, int n_in,
                              void* d_out, int out_size, void* d_ws, size_t ws_size,
                              hipStream_t stream) {
    const float* x = (const float*)d_in[0];       // [8, 8192] fp32
    const float* W = (const float*)d_in[1];       // [8192, 8192] fp32
    float* out = (float*)d_out;                   // [8, 8192] fp32

    // ws layout: [0,16K) double partials[2048]; [16K,+8) scalars; [32K,+256K) x_hat
    double* partials = (double*)d_ws;
    float* scal = (float*)((char*)d_ws + 16384);
    float* xh = (float*)((char*)d_ws + 32768);

    const int n4 = (M_DIM * K_DIM) / 4;   // 16,777,216 float4

    k_abssum<<<RED_BLOCKS, 256, 0, stream>>>((const float4*)W, partials, n4);
    k_final<<<1, 256, 0, stream>>>(partials, RED_BLOCKS, scal);
    k_actq<<<(N_DIM * K_DIM) / 256, 256, 0, stream>>>(x, xh);
    k_gemm<<<M_DIM / 16, 256, 0, stream>>>(W, xh, scal, out);
}